// Round 19
// baseline (68.051 us; speedup 1.0000x reference)
//
#include <hip/hip_runtime.h>
#include <hip/hip_bf16.h>
#include <cstdint>

// STFT as im2col GEMM:  C[b,c,t] = sum_n K[c,n] * xpad[b, t*HOP+n]
// R18 = R14's GEMM core as a clean standalone kernel (BM=256 x BN=128 x BK=32,
// 3-slot 72KB ring -> 2 blocks/CU, stage-2-ahead counted vmcnt(3), one barrier
// per K-tile) + R17's fused prep and Nyquist-skip edge kernel.
// Tests: counted-ring x 2-blocks/CU (R5 = ring@1blk 48.6us; R9 = drain@2blk 47.2us).

#define HOP 256
#define NFFT 1024
#define FB 513
#define NT 1025
#define NBATCH 16
#define MCH 1026
#define MP2 1280         // padded channel rows in workspace A
#define SIGLEN 262144
#define SIGP 263168      // reflect-padded length
#define BM 256
#define BN 128
#define BK 32
#define NKT 32           // K tiles (1024 / 32)
#define A_T 16384        // A tile: 256 rows * 64B
#define B_T 8192         // B tile: 128 rows * 64B
#define SLOT_BYTES (A_T + B_T)          // 24 KB
#define LDS_BYTES (3 * SLOT_BYTES)      // 72 KB -> 2 blocks/CU

typedef __attribute__((ext_vector_type(8))) short short8;
typedef __attribute__((ext_vector_type(4))) float f32x4;
typedef unsigned int u32;

__device__ __forceinline__ unsigned short f2bf(float f) {
  u32 u = __float_as_uint(f);
  u = (u + 0x7FFFu + ((u >> 16) & 1u)) >> 16;   // RNE
  return (unsigned short)u;
}
__device__ __forceinline__ float bf2f(unsigned short s) {
  return __uint_as_float(((u32)s) << 16);
}

// ---- fused prologue (verified R10/R15/R17) ----
#define NA_BLK 640
#define NS_BLK 2056
__global__ __launch_bounds__(256) void prep_all(const float* __restrict__ kern,
                                                const float* __restrict__ sig,
                                                unsigned short* __restrict__ A,
                                                unsigned short* __restrict__ S) {
  if (blockIdx.x < NA_BLK) {
    size_t i8 = ((size_t)blockIdx.x * 256 + threadIdx.x) * 8;
    int row = (int)(i8 >> 10);
    int col = (int)(i8 & 1023);
    short8 v = {0, 0, 0, 0, 0, 0, 0, 0};
    if (row < MCH) {
      int f = row >> 1, ri = row & 1;
      const float* s = kern + ((size_t)(ri * FB + f) << 10) + col;
#pragma unroll
      for (int e = 0; e < 8; ++e) v[e] = (short)f2bf(s[e]);
    }
    *(short8*)(A + i8) = v;
  } else {
    size_t i8 = ((size_t)(blockIdx.x - NA_BLK) * 256 + threadIdx.x) * 8;
    int b = (int)(i8 / SIGP);
    int i = (int)(i8 - (size_t)b * SIGP);
    const float* sb = sig + (size_t)b * SIGLEN;
    short8 v;
#pragma unroll
    for (int e = 0; e < 8; ++e) {
      int j = i + e - 512;
      j = (j < 0) ? -j : j;
      j = (j >= SIGLEN) ? (2 * SIGLEN - 2 - j) : j;
      v[e] = (short)f2bf(sb[j]);
    }
    *(short8*)(S + i8) = v;
  }
}

// async 16B global->LDS. LDS dest is wave-uniform; HW adds lane*16.
__device__ __forceinline__ void async16(void* lds, const void* g) {
  __builtin_amdgcn_global_load_lds(
      (const __attribute__((address_space(1))) u32*)g,
      (__attribute__((address_space(3))) u32*)lds, 16, 0, 0);
}

// ---- main GEMM (R14 core) ----
// 512 thr = 8 waves (wr=wid>>1 over M quarters, wc=wid&1 over N halves),
// wave = 64x64, 16 MFMA + 8 ds_read + 3 stage-loads per K-tile.
// 64B rows; involutive swizzle p = q ^ (((q>>7)&3)<<4) (0 conflicts measured;
// source stays 64B-line coalesced). Linear gload_lds dest (rule 21).
__global__ __launch_bounds__(512, 4) void stft_mm(const unsigned short* __restrict__ A,
                                                  const unsigned short* __restrict__ S,
                                                  float* __restrict__ out) {
  extern __shared__ char smem[];

  const int tid = threadIdx.x;
  const int lane = tid & 63;
  const int wid = tid >> 6;
  const int wr = wid >> 1;   // 0..3  (M quarter)
  const int wc = wid & 1;    // 0..1  (N half)
  const int lr = lane & 15;
  const int g16 = lane >> 4;

  // bijective XCD-chunk swizzle: nwg = 512 = 8 * 64
  const int bid = blockIdx.x;
  const int wg = (bid & 7) * 64 + (bid >> 3);
  const int mt = wg & 3;
  const int r2 = wg >> 2;
  const int nt = r2 & 7;
  const int b  = r2 >> 3;

  const int c0 = mt * BM;    // 0..768
  const int t0 = nt * BN;    // 0..896

  const char* Ab = (const char*)A;
  const char* Sb = (const char*)(S + (size_t)b * SIGP);

  // Stage K-tile kt into ring slot s. A: 1024 granules (2/thread); B: 512 (1/thread).
#define STAGE_TILE(kt, s)                                                      \
  {                                                                            \
    char* As_ = smem + (s) * SLOT_BYTES;                                       \
    char* Bs_ = As_ + A_T;                                                     \
    _Pragma("unroll") for (int j = 0; j < 2; ++j) {                            \
      const int G0 = j * 512 + wid * 64;                                       \
      u32 p = (u32)(G0 + lane) * 16u;                                          \
      u32 q = p ^ (((p >> 7) & 3u) << 4);                                      \
      const char* src = Ab + ((size_t)(c0 + (int)(q >> 6)) << 11)              \
                           + (kt) * 64 + (int)(q & 63u);                       \
      async16(As_ + (size_t)G0 * 16u, src);                                    \
    }                                                                          \
    {                                                                          \
      const int G0 = wid * 64;                                                 \
      u32 p = (u32)(G0 + lane) * 16u;                                          \
      u32 q = p ^ (((p >> 7) & 3u) << 4);                                      \
      const char* src = Sb + ((size_t)(t0 + (int)(q >> 6)) << 9)               \
                           + (kt) * 64 + (int)(q & 63u);                       \
      async16(Bs_ + (size_t)G0 * 16u, src);                                    \
    }                                                                          \
  }

  // prologue: fill slots 0,1 (6 loads/thread); gate tile0 landed (leave tile1)
  STAGE_TILE(0, 0)
  STAGE_TILE(1, 1)
  asm volatile("s_waitcnt vmcnt(3)" ::: "memory");
  __builtin_amdgcn_s_barrier();
  asm volatile("" ::: "memory");

  // per-lane SWIZZLED read offsets (loop-invariant)
  u32 pa[4], pb[4];
#pragma unroll
  for (int mi = 0; mi < 4; ++mi) {
    u32 q = (u32)((wr * 64 + mi * 16 + lr) * 64 + g16 * 16);
    pa[mi] = q ^ (((q >> 7) & 3u) << 4);
  }
#pragma unroll
  for (int ni = 0; ni < 4; ++ni) {
    u32 q = (u32)((wc * 64 + ni * 16 + lr) * 64 + g16 * 16);
    pb[ni] = q ^ (((q >> 7) & 3u) << 4);
  }

  f32x4 acc[4][4] = {};

#pragma unroll
  for (int k = 0; k < NKT; ++k) {
    const char* As = smem + (k % 3) * SLOT_BYTES;
    const char* Bs = As + A_T;

    // ds-reads of tile k (landed: gated at end of k-1; visible via barrier)
    short8 af[4], bfv[4];
#pragma unroll
    for (int mi = 0; mi < 4; ++mi) af[mi] = *(const short8*)(As + pa[mi]);
#pragma unroll
    for (int ni = 0; ni < 4; ++ni) bfv[ni] = *(const short8*)(Bs + pb[ni]);

    // stage tile k+2 into slot (k+2)%3 == (k-1)%3 (readers done before barrier k-1)
    if (k + 2 < NKT) STAGE_TILE(k + 2, (k + 2) % 3)

    // 16 MFMA while staging loads fly
#pragma unroll
    for (int mi = 0; mi < 4; ++mi)
#pragma unroll
      for (int ni = 0; ni < 4; ++ni)
        acc[mi][ni] = __builtin_amdgcn_mfma_f32_16x16x32_bf16(
            af[mi], bfv[ni], acc[mi][ni], 0, 0, 0);

    // gate: tile k+1 landed (tile k+2's 3 loads stay in flight); then barrier
    if (k + 1 < NKT) {
      if (k <= NKT - 3) asm volatile("s_waitcnt vmcnt(3)" ::: "memory");
      else              asm volatile("s_waitcnt vmcnt(0)" ::: "memory");
      __builtin_amdgcn_s_barrier();
      asm volatile("" ::: "memory");
    }
  }
#undef STAGE_TILE

  // epilogue: D row (lane>>4)*4+r = c' (paired), col lane&15 = t. No masks needed.
#pragma unroll
  for (int mi = 0; mi < 4; ++mi) {
    const int cb = c0 + wr * 64 + mi * 16 + g16 * 4;   // even
    const int f0 = cb >> 1;                            // < 512
#pragma unroll
    for (int ni = 0; ni < 4; ++ni) {
      const int t = t0 + wc * 64 + ni * 16 + lr;       // < 1024
      *(float2*)(out + ((((size_t)b * FB + f0) * NT + t) << 1)) =
          make_float2(acc[mi][ni][0], acc[mi][ni][1]);
      *(float2*)(out + ((((size_t)b * FB + f0 + 1) * NT + t) << 1)) =
          make_float2(acc[mi][ni][2], acc[mi][ni][3]);
    }
  }
}

// ---- edge kernel (R17): f=512 all t (REAL ONLY -- imag row ~ 0), and
// t=1024 all f (both rows). One wave per output point, bf16 workspace. ----
__global__ __launch_bounds__(256) void stft_edge(const unsigned short* __restrict__ A,
                                                 const unsigned short* __restrict__ S,
                                                 float* __restrict__ out) {
  const int wv = blockIdx.x * 4 + (threadIdx.x >> 6);
  const int lane = threadIdx.x & 63;

  if (wv < NBATCH * NT) {
    // ---- slice a: f = 512 (Nyquist). Imag kernel row ~ 0 -> d1 := 0 ----
    const int b = wv / NT, t = wv - b * NT;
    const unsigned short* w  = S + (size_t)b * SIGP + (size_t)t * HOP + lane * 16;
    const unsigned short* r0 = A + ((size_t)1024 << 10) + lane * 16;  // row 2*512
    short8 wv0 = *(const short8*)w,  wv1 = *(const short8*)(w + 8);
    short8 a0  = *(const short8*)r0, a1  = *(const short8*)(r0 + 8);
    float d0 = 0.f;
#pragma unroll
    for (int e = 0; e < 8; ++e) {
      d0 += bf2f((unsigned short)a0[e]) * bf2f((unsigned short)wv0[e]) +
            bf2f((unsigned short)a1[e]) * bf2f((unsigned short)wv1[e]);
    }
#pragma unroll
    for (int m = 32; m; m >>= 1) d0 += __shfl_xor(d0, m);
    if (lane == 0)
      *(float2*)(out + ((((size_t)b * FB + (FB - 1)) * NT + t) << 1)) =
          make_float2(d0, 0.0f);
  } else {
    // ---- slice b: t = 1024, f = 0..512 (both rows) ----
    const int u = wv - NBATCH * NT;
    const int b = u / FB, f = u - b * FB, t = NT - 1;
    const unsigned short* w  = S + (size_t)b * SIGP + (size_t)t * HOP + lane * 16;
    const unsigned short* r0 = A + ((size_t)(2 * f) << 10) + lane * 16;
    const unsigned short* r1 = r0 + 1024;
    short8 wv0 = *(const short8*)w,  wv1 = *(const short8*)(w + 8);
    short8 a0  = *(const short8*)r0, a1  = *(const short8*)(r0 + 8);
    short8 b0  = *(const short8*)r1, b1  = *(const short8*)(r1 + 8);
    float d0 = 0.f, d1 = 0.f;
#pragma unroll
    for (int e = 0; e < 8; ++e) {
      float x0 = bf2f((unsigned short)wv0[e]), x1 = bf2f((unsigned short)wv1[e]);
      d0 += bf2f((unsigned short)a0[e]) * x0 + bf2f((unsigned short)a1[e]) * x1;
      d1 += bf2f((unsigned short)b0[e]) * x0 + bf2f((unsigned short)b1[e]) * x1;
    }
#pragma unroll
    for (int m = 32; m; m >>= 1) {
      d0 += __shfl_xor(d0, m);
      d1 += __shfl_xor(d1, m);
    }
    if (lane == 0)
      *(float2*)(out + ((((size_t)b * FB + f) * NT + t) << 1)) = make_float2(d0, d1);
  }
}

extern "C" void kernel_launch(void* const* d_in, const int* in_sizes, int n_in,
                              void* d_out, int out_size, void* d_ws, size_t ws_size,
                              hipStream_t stream) {
  const float* sig = (const float*)d_in[0];    // (16, 262144) f32
  const float* kern = (const float*)d_in[1];   // (1026, 1024) f32
  float* out = (float*)d_out;                  // (16, 513, 1025, 2) f32

  unsigned short* wsA = (unsigned short*)d_ws;               // 1280*1024 bf16
  unsigned short* wsS = wsA + (size_t)MP2 * NFFT;            // 16*263168 bf16
  // ws use: (1280*1024 + 16*263168)*2 = 11,042,816 bytes

  (void)hipFuncSetAttribute((const void*)stft_mm,
                            hipFuncAttributeMaxDynamicSharedMemorySize, LDS_BYTES);

  prep_all<<<dim3(NA_BLK + NS_BLK), 256, 0, stream>>>(kern, sig, wsA, wsS);
  stft_mm<<<dim3(4 * 8 * NBATCH), 512, LDS_BYTES, stream>>>(wsA, wsS, out);
  // edge waves: 16*1025 + 16*513 = 24608 = 6152 blocks * 4 waves (exact)
  stft_edge<<<dim3((NBATCH * NT + NBATCH * FB) / 4), 256, 0, stream>>>(wsA, wsS, out);
}

// Round 20
// 60.029 us; speedup vs baseline: 1.1336x; 1.1336x over previous
//
#include <hip/hip_runtime.h>
#include <hip/hip_bf16.h>
#include <cstdint>

// STFT as im2col GEMM:  C[b,c,t] = sum_n K[c,n] * xpad[b, t*HOP+n]
// R19 = R17 restored (best measured: 60.08us).
// Main GEMM (R10 schedule + LDS-transposed epilogue): channels 0..1023 x
// frames 0..1023. Nyquist pair (f=512) and last frame (t=1024) -> stft_edge
// (bf16 workspace; Nyquist-imag skipped: row ~ 0, <=1e-10 error).

#define HOP 256
#define NFFT 1024
#define FB 513
#define NT 1025
#define NBATCH 16
#define MCH 1026
#define MP2 1280
#define SIGLEN 262144
#define SIGP 263168
#define BM 256
#define BN 256
#define BK 32
#define NKT 32
#define A_BYTES 16384    // 256 rows * 64B
#define B_BYTES 16384
#define SLOT_BYTES (A_BYTES + B_BYTES)     // 32 KB
#define LDS_BYTES (3 * SLOT_BYTES)         // 96 KB

typedef __attribute__((ext_vector_type(8))) short short8;
typedef __attribute__((ext_vector_type(4))) float f32x4;
typedef unsigned int u32;

__device__ __forceinline__ unsigned short f2bf(float f) {
  u32 u = __float_as_uint(f);
  u = (u + 0x7FFFu + ((u >> 16) & 1u)) >> 16;   // RNE
  return (unsigned short)u;
}
__device__ __forceinline__ float bf2f(unsigned short s) {
  return __uint_as_float(((u32)s) << 16);
}

// ---- fused prologue (verified R10/R15/R17) ----
#define NA_BLK 640
#define NS_BLK 2056
__global__ __launch_bounds__(256) void prep_all(const float* __restrict__ kern,
                                                const float* __restrict__ sig,
                                                unsigned short* __restrict__ A,
                                                unsigned short* __restrict__ S) {
  if (blockIdx.x < NA_BLK) {
    size_t i8 = ((size_t)blockIdx.x * 256 + threadIdx.x) * 8;
    int row = (int)(i8 >> 10);
    int col = (int)(i8 & 1023);
    short8 v = {0, 0, 0, 0, 0, 0, 0, 0};
    if (row < MCH) {
      int f = row >> 1, ri = row & 1;
      const float* s = kern + ((size_t)(ri * FB + f) << 10) + col;
#pragma unroll
      for (int e = 0; e < 8; ++e) v[e] = (short)f2bf(s[e]);
    }
    *(short8*)(A + i8) = v;
  } else {
    size_t i8 = ((size_t)(blockIdx.x - NA_BLK) * 256 + threadIdx.x) * 8;
    int b = (int)(i8 / SIGP);
    int i = (int)(i8 - (size_t)b * SIGP);
    const float* sb = sig + (size_t)b * SIGLEN;
    short8 v;
#pragma unroll
    for (int e = 0; e < 8; ++e) {
      int j = i + e - 512;
      j = (j < 0) ? -j : j;
      j = (j >= SIGLEN) ? (2 * SIGLEN - 2 - j) : j;
      v[e] = (short)f2bf(sb[j]);
    }
    *(short8*)(S + i8) = v;
  }
}

// async 16B global->LDS. LDS dest is wave-uniform; HW adds lane*16.
__device__ __forceinline__ void async16(void* lds, const void* g) {
  __builtin_amdgcn_global_load_lds(
      (const __attribute__((address_space(1))) u32*)g,
      (__attribute__((address_space(3))) u32*)lds, 16, 0, 0);
}

// ---- main GEMM (R10 schedule + LDS-transposed epilogue) ----
__global__ __launch_bounds__(512, 2) void stft_mm(const unsigned short* __restrict__ A,
                                                  const unsigned short* __restrict__ S,
                                                  float* __restrict__ out) {
  extern __shared__ char smem[];

  const int tid = threadIdx.x;
  const int lane = tid & 63;
  const int wid = tid >> 6;
  const int wr = wid >> 2;   // 0..1  (M half: 128 rows)
  const int wc = wid & 3;    // 0..3  (N quarter: 64 cols)
  const int lr = lane & 15;
  const int g16 = lane >> 4;

  // bijective XCD-chunk swizzle: nwg = 256 = 8 * 32
  const int bid = blockIdx.x;
  const int wg = (bid & 7) * 32 + (bid >> 3);
  const int mt = wg & 3;
  const int r2 = wg >> 2;
  const int nt = r2 & 3;
  const int b  = r2 >> 2;

  const int c0 = mt * BM;    // 0..768
  const int t0 = nt * BN;    // 0..768

  const char* Ab = (const char*)A;
  const char* Sb = (const char*)(S + (size_t)b * SIGP);

#define STAGE_A(kt, s)                                                         \
  {                                                                            \
    char* As_ = smem + (s) * SLOT_BYTES;                                       \
    _Pragma("unroll") for (int j = 0; j < 2; ++j) {                            \
      const int G0 = j * 512 + wid * 64;                                       \
      u32 p = (u32)(G0 + lane) * 16u;                                          \
      u32 q = p ^ (((p >> 7) & 3u) << 4);                                      \
      const char* src = Ab + ((size_t)(c0 + (int)(q >> 6)) << 11)              \
                           + (kt) * 64 + (int)(q & 63u);                       \
      async16(As_ + (size_t)G0 * 16u, src);                                    \
    }                                                                          \
  }
#define STAGE_B(kt, s)                                                         \
  {                                                                            \
    char* Bs_ = smem + (s) * SLOT_BYTES + A_BYTES;                             \
    _Pragma("unroll") for (int j = 0; j < 2; ++j) {                            \
      const int G0 = j * 512 + wid * 64;                                       \
      u32 p = (u32)(G0 + lane) * 16u;                                          \
      u32 q = p ^ (((p >> 7) & 3u) << 4);                                      \
      const char* src = Sb + ((size_t)(t0 + (int)(q >> 6)) << 9)               \
                           + (kt) * 64 + (int)(q & 63u);                       \
      async16(Bs_ + (size_t)G0 * 16u, src);                                    \
    }                                                                          \
  }

  STAGE_A(0, 0) STAGE_B(0, 0)
  STAGE_A(1, 1) STAGE_B(1, 1)
  asm volatile("s_waitcnt vmcnt(4)" ::: "memory");
  __builtin_amdgcn_s_barrier();
  asm volatile("" ::: "memory");

  u32 pa[8], pb[4];
#pragma unroll
  for (int mi = 0; mi < 8; ++mi) {
    u32 q = (u32)((wr * 128 + mi * 16 + lr) * 64 + g16 * 16);
    pa[mi] = q ^ (((q >> 7) & 3u) << 4);
  }
#pragma unroll
  for (int ni = 0; ni < 4; ++ni) {
    u32 q = (u32)((wc * 64 + ni * 16 + lr) * 64 + g16 * 16);
    pb[ni] = q ^ (((q >> 7) & 3u) << 4);
  }

  f32x4 acc[8][4] = {};

#pragma unroll
  for (int k = 0; k < NKT; ++k) {
    const char* As = smem + (k % 3) * SLOT_BYTES;
    const char* Bs = As + A_BYTES;
    const int ks = (k + 2) % 3;

    // ---------- phase 1 ----------
    short8 af[4], bfv[4];
#pragma unroll
    for (int mi = 0; mi < 4; ++mi) af[mi] = *(const short8*)(As + pa[mi]);
#pragma unroll
    for (int ni = 0; ni < 4; ++ni) bfv[ni] = *(const short8*)(Bs + pb[ni]);
    if (k + 2 < NKT) STAGE_A(k + 2, ks)
    __builtin_amdgcn_s_barrier();
    asm volatile("s_waitcnt lgkmcnt(0)" ::: "memory");
    __builtin_amdgcn_s_setprio(1);
#pragma unroll
    for (int mi = 0; mi < 4; ++mi)
#pragma unroll
      for (int ni = 0; ni < 4; ++ni)
        acc[mi][ni] = __builtin_amdgcn_mfma_f32_16x16x32_bf16(
            af[mi], bfv[ni], acc[mi][ni], 0, 0, 0);
    __builtin_amdgcn_s_setprio(0);
    __builtin_amdgcn_s_barrier();
    asm volatile("" ::: "memory");

    // ---------- phase 2 ----------
    short8 ag[4];
#pragma unroll
    for (int mi = 0; mi < 4; ++mi) ag[mi] = *(const short8*)(As + pa[4 + mi]);
    if (k + 2 < NKT) STAGE_B(k + 2, ks)
    __builtin_amdgcn_s_barrier();
    asm volatile("s_waitcnt lgkmcnt(0)" ::: "memory");
    __builtin_amdgcn_s_setprio(1);
#pragma unroll
    for (int mi = 0; mi < 4; ++mi)
#pragma unroll
      for (int ni = 0; ni < 4; ++ni)
        acc[4 + mi][ni] = __builtin_amdgcn_mfma_f32_16x16x32_bf16(
            ag[mi], bfv[ni], acc[4 + mi][ni], 0, 0, 0);
    __builtin_amdgcn_s_setprio(0);
    if (k + 2 < NKT)      asm volatile("s_waitcnt vmcnt(4)" ::: "memory");
    else if (k + 1 < NKT) asm volatile("s_waitcnt vmcnt(0)" ::: "memory");
    if (k + 1 < NKT) {
      __builtin_amdgcn_s_barrier();
      asm volatile("" ::: "memory");
    }
  }
#undef STAGE_A
#undef STAGE_B

  // ---- LDS-transposed epilogue: 2KB-contiguous global stores ----
  __syncthreads();                       // ring reads done; smem reusable
  float* chn = (float*)smem;             // 16*516*4 = 33,024 B
#pragma unroll
  for (int mi = 0; mi < 8; ++mi) {
#pragma unroll
    for (int ni = 0; ni < 4; ++ni) {
      const int t = wc * 64 + ni * 16 + lr;          // 0..255 local
#pragma unroll
      for (int rr = 0; rr < 2; ++rr) {               // fl = g16*2+rr
        const int row = wr * 8 + g16 * 2 + rr;
        *(float2*)(chn + row * 516 + t * 2) =
            make_float2(acc[mi][ni][2 * rr], acc[mi][ni][2 * rr + 1]);
      }
    }
    __syncthreads();
    const int Fbase = (c0 + mi * 16) >> 1;
#pragma unroll
    for (int p = 0; p < 4; ++p) {
      const int rowi = p * 4 + (tid >> 7);           // 0..15
      const int f = Fbase + (rowi >> 3) * 64 + (rowi & 7);
      const int e4 = (tid & 127) * 4;                // f32 offset within row
      const f32x4 v = *(const f32x4*)(chn + rowi * 516 + e4);
      float* gp = out + (((size_t)b * FB + f) * NT + t0) * 2 + e4;
      *(float2*)gp = make_float2(v[0], v[1]);
      *(float2*)(gp + 2) = make_float2(v[2], v[3]);
    }
    __syncthreads();
  }
}

// ---- edge kernel (bf16 ws): f=512 all t (REAL ONLY -- imag row ~ 0), and
// t=1024 all f (both rows). One wave per output point. ----
__global__ __launch_bounds__(256) void stft_edge(const unsigned short* __restrict__ A,
                                                 const unsigned short* __restrict__ S,
                                                 float* __restrict__ out) {
  const int wv = blockIdx.x * 4 + (threadIdx.x >> 6);
  const int lane = threadIdx.x & 63;

  if (wv < NBATCH * NT) {
    // ---- slice a: f = 512 (Nyquist). Imag kernel row ~ 0 -> d1 := 0 ----
    const int b = wv / NT, t = wv - b * NT;
    const unsigned short* w  = S + (size_t)b * SIGP + (size_t)t * HOP + lane * 16;
    const unsigned short* r0 = A + ((size_t)1024 << 10) + lane * 16;  // row 2*512
    short8 wv0 = *(const short8*)w,  wv1 = *(const short8*)(w + 8);
    short8 a0  = *(const short8*)r0, a1  = *(const short8*)(r0 + 8);
    float d0 = 0.f;
#pragma unroll
    for (int e = 0; e < 8; ++e) {
      d0 += bf2f((unsigned short)a0[e]) * bf2f((unsigned short)wv0[e]) +
            bf2f((unsigned short)a1[e]) * bf2f((unsigned short)wv1[e]);
    }
#pragma unroll
    for (int m = 32; m; m >>= 1) d0 += __shfl_xor(d0, m);
    if (lane == 0)
      *(float2*)(out + ((((size_t)b * FB + (FB - 1)) * NT + t) << 1)) =
          make_float2(d0, 0.0f);
  } else {
    // ---- slice b: t = 1024, f = 0..512 (both rows) ----
    const int u = wv - NBATCH * NT;
    const int b = u / FB, f = u - b * FB, t = NT - 1;
    const unsigned short* w  = S + (size_t)b * SIGP + (size_t)t * HOP + lane * 16;
    const unsigned short* r0 = A + ((size_t)(2 * f) << 10) + lane * 16;
    const unsigned short* r1 = r0 + 1024;
    short8 wv0 = *(const short8*)w,  wv1 = *(const short8*)(w + 8);
    short8 a0  = *(const short8*)r0, a1  = *(const short8*)(r0 + 8);
    short8 b0  = *(const short8*)r1, b1  = *(const short8*)(r1 + 8);
    float d0 = 0.f, d1 = 0.f;
#pragma unroll
    for (int e = 0; e < 8; ++e) {
      float x0 = bf2f((unsigned short)wv0[e]), x1 = bf2f((unsigned short)wv1[e]);
      d0 += bf2f((unsigned short)a0[e]) * x0 + bf2f((unsigned short)a1[e]) * x1;
      d1 += bf2f((unsigned short)b0[e]) * x0 + bf2f((unsigned short)b1[e]) * x1;
    }
#pragma unroll
    for (int m = 32; m; m >>= 1) {
      d0 += __shfl_xor(d0, m);
      d1 += __shfl_xor(d1, m);
    }
    if (lane == 0)
      *(float2*)(out + ((((size_t)b * FB + f) * NT + t) << 1)) = make_float2(d0, d1);
  }
}

extern "C" void kernel_launch(void* const* d_in, const int* in_sizes, int n_in,
                              void* d_out, int out_size, void* d_ws, size_t ws_size,
                              hipStream_t stream) {
  const float* sig = (const float*)d_in[0];    // (16, 262144) f32
  const float* kern = (const float*)d_in[1];   // (1026, 1024) f32
  float* out = (float*)d_out;                  // (16, 513, 1025, 2) f32

  unsigned short* wsA = (unsigned short*)d_ws;               // 1280*1024 bf16
  unsigned short* wsS = wsA + (size_t)MP2 * NFFT;            // 16*263168 bf16
  // ws use: (1280*1024 + 16*263168)*2 = 11,042,816 bytes

  (void)hipFuncSetAttribute((const void*)stft_mm,
                            hipFuncAttributeMaxDynamicSharedMemorySize, LDS_BYTES);

  prep_all<<<dim3(NA_BLK + NS_BLK), 256, 0, stream>>>(kern, sig, wsA, wsS);
  stft_mm<<<dim3(4 * 4 * NBATCH), 512, LDS_BYTES, stream>>>(wsA, wsS, out);
  // edge waves: 16*1025 + 16*513 = 24608 = 6152 blocks * 4 waves (exact)
  stft_edge<<<dim3((NBATCH * NT + NBATCH * FB) / 4), 256, 0, stream>>>(wsA, wsS, out);
}